// Round 12
// baseline (7470.096 us; speedup 1.0000x reference)
//
#include <hip/hip_runtime.h>
#include <hip/hip_fp16.h>

#define TL 2048

typedef __attribute__((ext_vector_type(8))) short bfx8;
typedef __attribute__((ext_vector_type(4))) float fx4;

__device__ __forceinline__ float sigf(float x){ return __builtin_amdgcn_rcpf(1.0f + __expf(-x)); }
__device__ __forceinline__ float tanhff(float x){ return fmaf(2.0f, sigf(2.0f*x), -1.0f); }

template<int CTRL>
__device__ __forceinline__ float dpp_xadd(float v){
  int s = __builtin_amdgcn_update_dpp(0, __float_as_int(v), CTRL, 0xF, 0xF, true);
  return v + __int_as_float(s);
}
__device__ __forceinline__ float bperm(float v, int srclane){
  return __int_as_float(__builtin_amdgcn_ds_bpermute(srclane << 2, __float_as_int(v)));
}
__device__ __forceinline__ unsigned short f2bf(float f){   // RNE fp32->bf16
  unsigned int u = __float_as_uint(f);
  u += 0x7fffu + ((u >> 16) & 1u);
  return (unsigned short)(u >> 16);
}
__device__ __forceinline__ float dot4(float4 a, float4 b, float acc){
  acc = fmaf(a.x, b.x, acc); acc = fmaf(a.y, b.y, acc);
  acc = fmaf(a.z, b.z, acc); acc = fmaf(a.w, b.w, acc);
  return acc;
}
// LDS-only barrier: do NOT drain vmcnt (global h-stores stay in flight).
__device__ __forceinline__ void barrier_lgkm(){
  asm volatile("s_waitcnt lgkmcnt(0)\ns_barrier" ::: "memory");
}
__device__ __forceinline__ bfx8 pack8(const float* p){
  bfx8 r;
  #pragma unroll
  for (int i = 0; i < 8; ++i) r[i] = (short)f2bf(p[i]);
  return r;
}
// ---- fp8 e4m3 (OCP) helpers: HW cvt on gfx950, software fallback. ----
__device__ __forceinline__ unsigned char f2fp8(float f){
#if __has_builtin(__builtin_amdgcn_cvt_pk_fp8_f32)
  return (unsigned char)(__builtin_amdgcn_cvt_pk_fp8_f32(f, f, 0, false) & 0xffu);
#else
  const unsigned u = __float_as_uint(f);
  const unsigned s = (u >> 24) & 0x80u;
  const float a = __uint_as_float(u & 0x7fffffffu);
  if (a >= 448.0f) return (unsigned char)(s | 0x7Eu);
  if (a < 0.015625f){                       // below min normal 2^-6
    int q = (int)rintf(a * 512.0f);         // subnormal steps 2^-9 (RNE)
    if (q > 8) q = 8;
    return (unsigned char)(s | (unsigned)q);
  }
  unsigned b = __float_as_uint(a);
  b += 0x0007FFFFu + ((b >> 20) & 1u);      // RNE into 3-bit mantissa
  const int e4 = (int)((b >> 23) & 0xffu) - 120;
  const int m3 = (int)((b >> 20) & 7u);
  if (e4 > 15 || (e4 == 15 && m3 == 7)) return (unsigned char)(s | 0x7Eu);
  return (unsigned char)(s | ((unsigned)e4 << 3) | (unsigned)m3);
#endif
}
__device__ __forceinline__ unsigned pkbf16(float a, float b){
  unsigned r;
  asm volatile("v_cvt_pk_bf16_f32 %0, %1, %2" : "=v"(r) : "v"(a), "v"(b));
  return r;
}
__device__ __forceinline__ float fp8d_sw(unsigned byte){
  const unsigned s = (byte & 0x80u) << 24;
  const unsigned e = (byte >> 3) & 0xFu;
  const unsigned m = byte & 7u;
  if (e == 0) return __uint_as_float(s | 0x3F800000u) < 0.f
                   ? -(float)m * 0.001953125f : (float)m * 0.001953125f;
  return __uint_as_float(s | ((e + 120u) << 23) | (m << 20));
}
// 8 fp8 (uint2) -> 8 bf16 fragment (exact: fp8 values are bf16-representable)
__device__ __forceinline__ bfx8 fp8x8_to_bf16x8(uint2 v){
#if __has_builtin(__builtin_amdgcn_cvt_pk_f32_fp8)
  typedef float fv2 __attribute__((ext_vector_type(2)));
  fv2 d0 = __builtin_amdgcn_cvt_pk_f32_fp8((int)v.x, false);
  fv2 d1 = __builtin_amdgcn_cvt_pk_f32_fp8((int)v.x, true);
  fv2 d2 = __builtin_amdgcn_cvt_pk_f32_fp8((int)v.y, false);
  fv2 d3 = __builtin_amdgcn_cvt_pk_f32_fp8((int)v.y, true);
  uint4 w{pkbf16(d0[0], d0[1]), pkbf16(d1[0], d1[1]),
          pkbf16(d2[0], d2[1]), pkbf16(d3[0], d3[1])};
  bfx8 r; __builtin_memcpy(&r, &w, 16); return r;
#else
  float f[8];
  f[0]=fp8d_sw(v.x&0xff); f[1]=fp8d_sw((v.x>>8)&0xff);
  f[2]=fp8d_sw((v.x>>16)&0xff); f[3]=fp8d_sw(v.x>>24);
  f[4]=fp8d_sw(v.y&0xff); f[5]=fp8d_sw((v.y>>8)&0xff);
  f[6]=fp8d_sw((v.y>>16)&0xff); f[7]=fp8d_sw(v.y>>24);
  return pack8(f);
#endif
}

// Uber-kernel; segments selected per-block by [nL1 | nL2 | nL3]:
//   blockIdx [0,nL1)            : L1 scan (f16-resident weights), h1 out FP8
//   blockIdx [nL1,nL1+nL2)      : L2 scan, MFMA proj on fp8->bf16 h1
//   blockIdx [nL1+nL2, +nL3)    : L3 scan, ONE WAVE PER CHAIN (barrier-free)
// HISTORY (do not regress):
//  - launch_bounds must stay (512,2): (512,4) caps VGPR at 64 -> spill (r1).
//  - MFMA-batched L1 (r4-r6) is latency-bound at 1 WG/CU. Reverted.
//  - r8: barrier-free 1-wave L3. r9: f16-resident L1 weights (mids ->1425).
//  - r10/r11: issue-count cuts are NULL -> scans latency-bound ~1670cyc/step.
//    k0 @1blk/CU == mids @2blk/CU proves it. Only lever left: fewer
//    dispatches.
//  - r12: h1 interface stored FP8 e4m3 (L1 recurrence stays fp32; o2 stays
//    bf16) -> full-B h1 (128MB) + o2 (128MB) = 256MB fits proven ws
//    (>=276.9MB) -> NO chunk pipeline: 3 stage-dispatches + head.
__global__ __launch_bounds__(512, 2) void mega_kernel(
    int nL1, int nL2, int nL3, int cb1, int cb2, int cb3, int p1, int p2, int p3,
    const float* __restrict__ x,
    const float* __restrict__ Wih1, const float* __restrict__ Whh1,
    const float* __restrict__ bih1, const float* __restrict__ bhh1,
    const float* __restrict__ Wih2, const float* __restrict__ Whh2,
    const float* __restrict__ bih2, const float* __restrict__ bhh2,
    const float* __restrict__ Wih3, const float* __restrict__ Whh3,
    const float* __restrict__ bih3, const float* __restrict__ bhh3,
    unsigned char* __restrict__ h1r0, unsigned char* __restrict__ h1r1,
    unsigned short* __restrict__ o2r0, unsigned short* __restrict__ o2r1,
    float* __restrict__ sums)
{
  __shared__ __align__(16) unsigned char smem[34816];
  const int tid  = threadIdx.x;
  const int bid  = blockIdx.x;
  const int lane = tid & 63;
  const int wv   = tid >> 6;

  if (bid < nL1){
    // ================= L1: H=128, D=2 folded. WG = one (b,dir) chain. ======
    const int bloc = bid >> 1, dir = bid & 1;
    unsigned char* h1o = p1 ? h1r1 : h1r0;
    const int kc = tid & 3, u = tid >> 2;

    // Weights: 4 gate-rows x 32 K-elems as f16 pairs -> 64 VGPRs, RESIDENT.
    __half2 wh[4][16];
    const float* Wh = Whh1 + dir * 65536;
    #pragma unroll
    for (int g = 0; g < 4; ++g){
      const float* row = Wh + (g * 128 + u) * 128 + kc * 32;
      #pragma unroll
      for (int q = 0; q < 8; ++q){
        const int ro = (q + 2 * kc) & 7;
        const float4 t = *(const float4*)(row + ro * 4);
        wh[g][2 * q]     = __floats2half2_rn(t.x, t.y);
        wh[g][2 * q + 1] = __floats2half2_rn(t.z, t.w);
      }
    }
    float xwA[4], xwB[4], bs[4];
    #pragma unroll
    for (int g = 0; g < 4; ++g){
      const int r = g * 128 + u;
      xwA[g] = Wih1[dir * 1024 + r * 2];
      xwB[g] = Wih1[dir * 1024 + r * 2 + 1];
      bs[g]  = bih1[dir * 512 + r] + bhh1[dir * 512 + r];
    }
    float* xlds = (float*)smem;                  // 4096 f (full x row)
    float* hbuf = (float*)(smem + 16384);        // 2 x 128 f (fp32 state!)
    {
      const float* xb = x + (size_t)(cb1 + bloc) * (TL * 2);
      for (int idx = tid; idx < TL * 2; idx += 512) xlds[idx] = xb[idx];
    }
    if (tid < 128){ hbuf[tid] = 0.0f; hbuf[128 + tid] = 0.0f; }
    __syncthreads();

    float cst = 0.0f;
    for (int t = 0; t < TL; ++t){
      const int tt  = dir ? (TL - 1 - t) : t;
      const int cur = t & 1;
      const float4* hp = (const float4*)(hbuf + cur * 128) + kc * 8;
      float a0 = 0.f, a1 = 0.f, a2 = 0.f, a3 = 0.f;
      #pragma unroll
      for (int q = 0; q < 8; ++q){
        const float4 hv = hp[(q + 2 * kc) & 7];
        const __half2 w0a = wh[0][2*q], w0b = wh[0][2*q+1];
        const __half2 w1a = wh[1][2*q], w1b = wh[1][2*q+1];
        const __half2 w2a = wh[2][2*q], w2b = wh[2][2*q+1];
        const __half2 w3a = wh[3][2*q], w3b = wh[3][2*q+1];
        a0 = fmaf(__low2float(w0a), hv.x, a0); a0 = fmaf(__high2float(w0a), hv.y, a0);
        a0 = fmaf(__low2float(w0b), hv.z, a0); a0 = fmaf(__high2float(w0b), hv.w, a0);
        a1 = fmaf(__low2float(w1a), hv.x, a1); a1 = fmaf(__high2float(w1a), hv.y, a1);
        a1 = fmaf(__low2float(w1b), hv.z, a1); a1 = fmaf(__high2float(w1b), hv.w, a1);
        a2 = fmaf(__low2float(w2a), hv.x, a2); a2 = fmaf(__high2float(w2a), hv.y, a2);
        a2 = fmaf(__low2float(w2b), hv.z, a2); a2 = fmaf(__high2float(w2b), hv.w, a2);
        a3 = fmaf(__low2float(w3a), hv.x, a3); a3 = fmaf(__high2float(w3a), hv.y, a3);
        a3 = fmaf(__low2float(w3b), hv.z, a3); a3 = fmaf(__high2float(w3b), hv.w, a3);
      }
      a0 = dpp_xadd<0x4E>(dpp_xadd<0xB1>(a0));
      a1 = dpp_xadd<0x4E>(dpp_xadd<0xB1>(a1));
      a2 = dpp_xadd<0x4E>(dpp_xadd<0xB1>(a2));
      a3 = dpp_xadd<0x4E>(dpp_xadd<0xB1>(a3));
      if (kc == 0){
        const float x0 = xlds[tt * 2], x1 = xlds[tt * 2 + 1];
        const float p0 = a0 + fmaf(xwA[0], x0, fmaf(xwB[0], x1, bs[0]));
        const float p1 = a1 + fmaf(xwA[1], x0, fmaf(xwB[1], x1, bs[1]));
        const float p2 = a2 + fmaf(xwA[2], x0, fmaf(xwB[2], x1, bs[2]));
        const float p3 = a3 + fmaf(xwA[3], x0, fmaf(xwB[3], x1, bs[3]));
        const float ig = sigf(p0), fg = sigf(p1), gg = tanhff(p2), og = sigf(p3);
        cst = fmaf(fg, cst, ig * gg);
        const float h = og * tanhff(cst);
        hbuf[(cur ^ 1) * 128 + u] = h;                       // fp32 recurrence
        h1o[((size_t)bloc * TL + tt) * 256 + dir * 128 + u] = f2fp8(h);
      }
      barrier_lgkm();
    }

  } else if (bid < nL1 + nL2){
    // ================= L2: H=64; proj (K=256) via MFMA lookahead. ==========
    const int i2 = bid - nL1;
    const int bloc = i2 >> 1, dir = i2 & 1;
    const unsigned char* h1i = (p2 ? h1r1 : h1r0) + (size_t)bloc * TL * 256;
    unsigned short* o2o = p2 ? o2r1 : o2r0;
    const int kc = tid & 7, u = tid >> 3;

    float4 wr[4][2]; float bs[4];
    const float* WR = Whh2 + dir * 16384;
    #pragma unroll
    for (int tgt = 0; tgt < 4; ++tgt){
      const int row = tgt * 64 + u;
      wr[tgt][0] = *(const float4*)(WR + row * 64 + kc * 8);
      wr[tgt][1] = *(const float4*)(WR + row * 64 + kc * 8 + 4);
      bs[tgt] = bih2[dir * 256 + row] + bhh2[dir * 256 + row];
    }
    bfx8 Bf[2][8];
    const float* WP = Wih2 + dir * 65536;
    #pragma unroll
    for (int ntl = 0; ntl < 2; ++ntl){
      const int n = (2 * wv + ntl) * 16 + (lane & 15);
      #pragma unroll
      for (int Kf = 0; Kf < 8; ++Kf)
        Bf[ntl][Kf] = pack8(WP + n * 256 + Kf * 32 + (lane >> 4) * 8);
    }
    float* xs  = (float*)smem;                   // 2 bufs x 16 x 258 f
    float* h2b = (float*)(smem + 33024);         // 2 x 64 f
    if (tid < 64){ h2b[tid] = 0.0f; h2b[64 + tid] = 0.0f; }

    auto loadA = [&](int blk, uint2* a8){
      const int m  = lane & 15;
      const int pt = dir ? (TL - 1 - (blk * 16 + m)) : (blk * 16 + m);
      const unsigned char* base = h1i + (size_t)pt * 256 + (lane >> 4) * 8;
      #pragma unroll
      for (int Kf = 0; Kf < 8; ++Kf) a8[Kf] = *(const uint2*)(base + Kf * 32);
    };
    auto domfma = [&](uint2* a8, int buf){
      fx4 acc0 = {0.f,0.f,0.f,0.f}, acc1 = {0.f,0.f,0.f,0.f};
      #pragma unroll
      for (int Kf = 0; Kf < 8; ++Kf){
        const bfx8 av = fp8x8_to_bf16x8(a8[Kf]);
        acc0 = __builtin_amdgcn_mfma_f32_16x16x32_bf16(av, Bf[0][Kf], acc0, 0, 0, 0);
        acc1 = __builtin_amdgcn_mfma_f32_16x16x32_bf16(av, Bf[1][Kf], acc1, 0, 0, 0);
      }
      const int c0 = (2 * wv) * 16 + (lane & 15);
      #pragma unroll
      for (int rr = 0; rr < 4; ++rr){
        const int row = (lane >> 4) * 4 + rr;
        xs[buf * 4128 + row * 258 + c0]      = acc0[rr];
        xs[buf * 4128 + row * 258 + c0 + 16] = acc1[rr];
      }
    };

    uint2 a8[8];
    loadA(0, a8); domfma(a8, 0);
    loadA(1, a8); domfma(a8, 1);
    __syncthreads();

    float cst = 0.0f;
    uint2 pf[8];
    for (int B = 0; B < 128; ++B){
      if (B + 2 < 128) loadA(B + 2, pf);      // issue; consumed after the 16 steps
      const int pb = B & 1;
      for (int s = 0; s < 16; ++s){
        const int t  = B * 16 + s;
        const int tt = dir ? (TL - 1 - t) : t;
        const int cur = t & 1;
        const float4* hv4 = (const float4*)(h2b + cur * 64) + kc * 2;
        const float4 hA = hv4[0], hB = hv4[1];
        float a0 = dot4(wr[0][1], hB, dot4(wr[0][0], hA, 0.f));
        float a1 = dot4(wr[1][1], hB, dot4(wr[1][0], hA, 0.f));
        float a2 = dot4(wr[2][1], hB, dot4(wr[2][0], hA, 0.f));
        float a3 = dot4(wr[3][1], hB, dot4(wr[3][0], hA, 0.f));
        // 8-way kc reduce entirely in the VALU pipe (r11).
        a0 = dpp_xadd<0x141>(dpp_xadd<0x4E>(dpp_xadd<0xB1>(a0)));
        a1 = dpp_xadd<0x141>(dpp_xadd<0x4E>(dpp_xadd<0xB1>(a1)));
        a2 = dpp_xadd<0x141>(dpp_xadd<0x4E>(dpp_xadd<0xB1>(a2)));
        a3 = dpp_xadd<0x141>(dpp_xadd<0x4E>(dpp_xadd<0xB1>(a3)));
        if (kc == 0){
          const float* xr = xs + pb * 4128 + s * 258 + u;
          const float ig = sigf(a0 + xr[0]   + bs[0]);
          const float fg = sigf(a1 + xr[64]  + bs[1]);
          const float gg = tanhff(a2 + xr[128] + bs[2]);
          const float og = sigf(a3 + xr[192] + bs[3]);
          cst = fmaf(fg, cst, ig * gg);
          const float h = og * tanhff(cst);
          h2b[(cur ^ 1) * 64 + u] = h;
          o2o[((size_t)bloc * TL + tt) * 128 + dir * 64 + u] = f2bf(h);
        }
        barrier_lgkm();
      }
      if (B + 2 < 128) domfma(pf, pb);        // fills buf pb for block B+2
    }

  } else {
    // ========== L3: H=16; ONE WAVE PER CHAIN, barrier-free (r8). ==========
    const int i3 = bid - nL1 - nL2;
    const int mm  = lane & 15;
    const int gg4 = lane >> 4;               // gate id (i,f,g,o) for this lane

    unsigned short* wlds = (unsigned short*)smem;   // 32768 B: [dir][64][128] bf16
    float* h3b = (float*)(smem + 32768);            // 4 ch x 2 x 16 f = 512 B
    for (int idx = tid; idx < 8192; idx += 512){
      const float2 v = *(const float2*)(Wih3 + idx * 2);
      const unsigned off = idx * 4u;
      const unsigned sw  = off ^ ((((off >> 8) & 7u)) << 4);
      *(unsigned*)((unsigned char*)wlds + sw) =
          (unsigned)f2bf(v.x) | ((unsigned)f2bf(v.y) << 16);
    }
    if (tid < 128) h3b[tid] = 0.0f;
    __syncthreads();
    if (wv >= 4) return;                      // idle waves exit; no barriers follow

    const int chain = i3 * 4 + wv;
    const int bloc = chain >> 1, dir = chain & 1;
    const unsigned short* o2i = (p3 ? o2r1 : o2r0) + (size_t)bloc * TL * 128;

    const float* WR = Whh3 + dir * 1024 + (gg4 * 16 + mm) * 16;
    const float4 wr0 = *(const float4*)(WR);
    const float4 wr1 = *(const float4*)(WR + 4);
    const float4 wr2 = *(const float4*)(WR + 8);
    const float4 wr3 = *(const float4*)(WR + 12);
    const float bsv = bih3[dir * 64 + gg4 * 16 + mm] + bhh3[dir * 64 + gg4 * 16 + mm];

    float* hme = h3b + wv * 32;

    uint4 a4[4];
    auto loadA3 = [&](int blk){
      const int pt = dir ? (TL - 1 - (blk * 16 + mm)) : (blk * 16 + mm);
      const unsigned short* bptr = o2i + (size_t)pt * 128 + (lane >> 4) * 8;
      #pragma unroll
      for (int Kf = 0; Kf < 4; ++Kf) a4[Kf] = *(const uint4*)(bptr + Kf * 32);
    };
    fx4 ac0, ac1, ac2, ac3;
    auto domfma3 = [&](){
      ac0 = fx4{0.f,0.f,0.f,0.f}; ac1 = fx4{0.f,0.f,0.f,0.f};
      ac2 = fx4{0.f,0.f,0.f,0.f}; ac3 = fx4{0.f,0.f,0.f,0.f};
      #pragma unroll
      for (int Kf = 0; Kf < 4; ++Kf){
        bfx8 av; __builtin_memcpy(&av, &a4[Kf], 16);
        #pragma unroll
        for (int gt = 0; gt < 4; ++gt){
          unsigned boff = dir * 16384u + (unsigned)(gt * 16 + mm) * 256u
                        + (unsigned)(Kf * 32 + (lane >> 4) * 8) * 2u;
          boff ^= ((unsigned)(mm & 7) << 4);
          bfx8 bv; __builtin_memcpy(&bv, (unsigned char*)wlds + boff, 16);
          if (gt == 0) ac0 = __builtin_amdgcn_mfma_f32_16x16x32_bf16(av, bv, ac0, 0,0,0);
          else if (gt == 1) ac1 = __builtin_amdgcn_mfma_f32_16x16x32_bf16(av, bv, ac1, 0,0,0);
          else if (gt == 2) ac2 = __builtin_amdgcn_mfma_f32_16x16x32_bf16(av, bv, ac2, 0,0,0);
          else ac3 = __builtin_amdgcn_mfma_f32_16x16x32_bf16(av, bv, ac3, 0,0,0);
        }
      }
    };

    loadA3(0); domfma3(); loadA3(1);

    float cst = 0.0f, msum = 0.0f;
    for (int B = 0; B < 128; ++B){
      #pragma unroll
      for (int s = 0; s < 16; ++s){
        const int t = B * 16 + s;
        const int cur = t & 1;
        const float* hb = hme + cur * 16;
        const float4 h0 = *(const float4*)(hb);
        const float4 h1 = *(const float4*)(hb + 4);
        const float4 h2 = *(const float4*)(hb + 8);
        const float4 h3v = *(const float4*)(hb + 12);
        const float rec = dot4(wr3, h3v, dot4(wr2, h2, dot4(wr1, h1, dot4(wr0, h0, 0.f))));
        const int src = (s >> 2) * 16 + mm;
        const float p0 = bperm(ac0[s & 3], src);
        const float p1 = bperm(ac1[s & 3], src);
        const float p2 = bperm(ac2[s & 3], src);
        const float p3 = bperm(ac3[s & 3], src);
        const float pj = (gg4 == 0) ? p0 : (gg4 == 1) ? p1 : (gg4 == 2) ? p2 : p3;
        const float pre = rec + pj + bsv;
        const float sg = sigf((gg4 == 2) ? 2.0f * pre : pre);
        const float act = (gg4 == 2) ? fmaf(2.0f, sg, -1.0f) : sg;
        const float gI = bperm(act, mm);
        const float gF = bperm(act, mm + 16);
        const float gG = bperm(act, mm + 32);
        const float gO = bperm(act, mm + 48);
        if (lane < 16){
          cst = fmaf(gF, cst, gI * gG);
          const float h = gO * tanhff(cst);
          hme[(cur ^ 1) * 16 + mm] = h;
          msum += h;
        }
      }
      if (B + 1 < 128){ domfma3(); if (B + 2 < 128) loadA3(B + 2); }
    }
    if (lane < 16) sums[(size_t)(cb3 + bloc) * 32 + dir * 16 + mm] = msum;
  }
}

// ---------------- head: mean (pre-summed) + MLP, one 64-thr WG per batch
__global__ __launch_bounds__(64) void head_kernel(
    const float* __restrict__ sums,
    const float* __restrict__ hW1, const float* __restrict__ hb1,
    const float* __restrict__ hW2, const float* __restrict__ hb2,
    const float* __restrict__ hW3, const float* __restrict__ hb3,
    float* __restrict__ out)
{
  __shared__ float m[32], h1s[64], h2s[16];
  const int tid = threadIdx.x, b = blockIdx.x;
  if (tid < 32) m[tid] = sums[b * 32 + tid] * (1.0f / 2048.0f);
  __syncthreads();
  {
    float a = hb1[tid];
    #pragma unroll
    for (int k = 0; k < 32; ++k) a = fmaf(m[k], hW1[tid * 32 + k], a);
    h1s[tid] = fmaxf(a, 0.0f);
  }
  __syncthreads();
  if (tid < 16){
    float a = hb2[tid];
    #pragma unroll
    for (int k = 0; k < 64; ++k) a = fmaf(h1s[k], hW2[tid * 64 + k], a);
    h2s[tid] = fmaxf(a, 0.0f);
  }
  __syncthreads();
  if (tid < 20){
    float a = hb3[tid];
    #pragma unroll
    for (int k = 0; k < 16; ++k) a = fmaf(h2s[k], hW3[tid * 16 + k], a);
    out[b * 20 + tid] = a;
  }
}

extern "C" void kernel_launch(void* const* d_in, const int* in_sizes, int n_in,
                              void* d_out, int out_size, void* d_ws, size_t ws_size,
                              hipStream_t stream) {
  (void)in_sizes; (void)n_in; (void)out_size;
  const float* x    = (const float*)d_in[0];
  const float* Wih1 = (const float*)d_in[1];
  const float* Whh1 = (const float*)d_in[2];
  const float* bih1 = (const float*)d_in[3];
  const float* bhh1 = (const float*)d_in[4];
  const float* Wih2 = (const float*)d_in[5];
  const float* Whh2 = (const float*)d_in[6];
  const float* bih2 = (const float*)d_in[7];
  const float* bhh2 = (const float*)d_in[8];
  const float* Wih3 = (const float*)d_in[9];
  const float* Whh3 = (const float*)d_in[10];
  const float* bih3 = (const float*)d_in[11];
  const float* bhh3 = (const float*)d_in[12];
  const float* hW1  = (const float*)d_in[13];
  const float* hb1  = (const float*)d_in[14];
  const float* hW2  = (const float*)d_in[15];
  const float* hb2  = (const float*)d_in[16];
  const float* hW3  = (const float*)d_in[17];
  const float* hb3  = (const float*)d_in[18];
  unsigned char* ws = (unsigned char*)d_ws;

  if (ws_size >= 268468224ull) {
    // ===== Flat schedule: full-B per stage, 3 dispatches + head. =====
    // h1 fp8 (256,2048,256) = 134,217,728 B | o2 bf16 (256,2048,128) =
    // 134,217,728 B | sums 32,768 B. Total 268,468,224 <= proven ws
    // (>=276,856,832, established round 3).
    unsigned char*  h1 = ws;
    unsigned short* o2 = (unsigned short*)(ws + 134217728u);
    float* sums = (float*)(ws + 268435456u);
    mega_kernel<<<dim3(512), dim3(512), 0, stream>>>(   // L1: all 512 chains
        512, 0, 0, 0, 0, 0, 0, 0, 0,
        x, Wih1, Whh1, bih1, bhh1, Wih2, Whh2, bih2, bhh2,
        Wih3, Whh3, bih3, bhh3, h1, h1, o2, o2, sums);
    mega_kernel<<<dim3(512), dim3(512), 0, stream>>>(   // L2: all 512 chains
        0, 512, 0, 0, 0, 0, 0, 0, 0,
        x, Wih1, Whh1, bih1, bhh1, Wih2, Whh2, bih2, bhh2,
        Wih3, Whh3, bih3, bhh3, h1, h1, o2, o2, sums);
    mega_kernel<<<dim3(128), dim3(512), 0, stream>>>(   // L3: 4 chains/WG
        0, 0, 128, 0, 0, 0, 0, 0, 0,
        x, Wih1, Whh1, bih1, bhh1, Wih2, Whh2, bih2, bhh2,
        Wih3, Whh3, bih3, bhh3, h1, h1, o2, o2, sums);
    head_kernel<<<dim3(256), dim3(64), 0, stream>>>(
        sums, hW1, hb1, hW2, hb2, hW3, hb3, (float*)d_out);
    return;
  }

  // ===== Fallback (unreachable given established ws bracket): fp8-h1 ring
  // pipeline, C=88, footprint 88*2MB + 32KB = 184.6MB.
  {
    const size_t C = 88;
    int cs[3] = {88, 84, 84};
    unsigned char*  h1r0 = ws;
    unsigned char*  h1r1 = h1r0 + C * (size_t)TL * 256;
    unsigned short* o2r0 = (unsigned short*)(ws + C * 1048576ull);
    unsigned short* o2r1 = o2r0 + C * (size_t)TL * 128;
    float* sums = (float*)(ws + C * 2097152ull);

    int co[3]; co[0] = 0;
    for (int i = 1; i < 3; ++i) co[i] = co[i - 1] + cs[i - 1];

    for (int k = 0; k < 5; ++k){
      const int a1 = (k < 3) ? cs[k] : 0;
      const int a2 = (k >= 1 && k < 4) ? cs[k - 1] : 0;
      const int a3 = (k >= 2) ? cs[k - 2] : 0;
      const int nL1 = 2 * a1, nL2 = 2 * a2, nL3 = a3 / 2;
      mega_kernel<<<dim3(nL1 + nL2 + nL3), dim3(512), 0, stream>>>(
          nL1, nL2, nL3,
          (k < 3) ? co[k] : 0, (k >= 1 && k < 4) ? co[k - 1] : 0,
          (k >= 2) ? co[k - 2] : 0,
          k & 1, (k + 1) & 1, k & 1,
          x, Wih1, Whh1, bih1, bhh1, Wih2, Whh2, bih2, bhh2,
          Wih3, Whh3, bih3, bhh3, h1r0, h1r1, o2r0, o2r1, sums);
    }
    head_kernel<<<dim3(256), dim3(64), 0, stream>>>(
        sums, hW1, hb1, hW2, hb2, hW3, hb3, (float*)d_out);
  }
}

// Round 13
// 5394.790 us; speedup vs baseline: 1.3847x; 1.3847x over previous
//
#include <hip/hip_runtime.h>
#include <hip/hip_fp16.h>

#define TL 2048

typedef __attribute__((ext_vector_type(8))) short bfx8;
typedef __attribute__((ext_vector_type(4))) float fx4;

__device__ __forceinline__ float sigf(float x){ return __builtin_amdgcn_rcpf(1.0f + __expf(-x)); }
__device__ __forceinline__ float tanhff(float x){ return fmaf(2.0f, sigf(2.0f*x), -1.0f); }

template<int CTRL>
__device__ __forceinline__ float dpp_xadd(float v){
  int s = __builtin_amdgcn_update_dpp(0, __float_as_int(v), CTRL, 0xF, 0xF, true);
  return v + __int_as_float(s);
}
__device__ __forceinline__ float bperm(float v, int srclane){
  return __int_as_float(__builtin_amdgcn_ds_bpermute(srclane << 2, __float_as_int(v)));
}
__device__ __forceinline__ unsigned short f2bf(float f){   // RNE fp32->bf16
  unsigned int u = __float_as_uint(f);
  u += 0x7fffu + ((u >> 16) & 1u);
  return (unsigned short)(u >> 16);
}
__device__ __forceinline__ float dot4(float4 a, float4 b, float acc){
  acc = fmaf(a.x, b.x, acc); acc = fmaf(a.y, b.y, acc);
  acc = fmaf(a.z, b.z, acc); acc = fmaf(a.w, b.w, acc);
  return acc;
}
// LDS-only barrier: do NOT drain vmcnt (global h-stores stay in flight).
__device__ __forceinline__ void barrier_lgkm(){
  asm volatile("s_waitcnt lgkmcnt(0)\ns_barrier" ::: "memory");
}
__device__ __forceinline__ bfx8 pack8(const float* p){
  bfx8 r;
  #pragma unroll
  for (int i = 0; i < 8; ++i) r[i] = (short)f2bf(p[i]);
  return r;
}
// ---- fp8 e4m3 (OCP) helpers: HW cvt on gfx950, software fallback. ----
__device__ __forceinline__ unsigned char f2fp8(float f){
#if __has_builtin(__builtin_amdgcn_cvt_pk_fp8_f32)
  return (unsigned char)(__builtin_amdgcn_cvt_pk_fp8_f32(f, f, 0, false) & 0xffu);
#else
  const unsigned u = __float_as_uint(f);
  const unsigned s = (u >> 24) & 0x80u;
  const float a = __uint_as_float(u & 0x7fffffffu);
  if (a >= 448.0f) return (unsigned char)(s | 0x7Eu);
  if (a < 0.015625f){                       // below min normal 2^-6
    int q = (int)rintf(a * 512.0f);         // subnormal steps 2^-9 (RNE)
    if (q > 8) q = 8;
    return (unsigned char)(s | (unsigned)q);
  }
  unsigned b = __float_as_uint(a);
  b += 0x0007FFFFu + ((b >> 20) & 1u);      // RNE into 3-bit mantissa
  const int e4 = (int)((b >> 23) & 0xffu) - 120;
  const int m3 = (int)((b >> 20) & 7u);
  if (e4 > 15 || (e4 == 15 && m3 == 7)) return (unsigned char)(s | 0x7Eu);
  return (unsigned char)(s | ((unsigned)e4 << 3) | (unsigned)m3);
#endif
}
__device__ __forceinline__ unsigned pkbf16(float a, float b){
  unsigned r;
  asm volatile("v_cvt_pk_bf16_f32 %0, %1, %2" : "=v"(r) : "v"(a), "v"(b));
  return r;
}
__device__ __forceinline__ float fp8d_sw(unsigned byte){
  const unsigned s = (byte & 0x80u) << 24;
  const unsigned e = (byte >> 3) & 0xFu;
  const unsigned m = byte & 7u;
  if (e == 0) return __uint_as_float(s | 0x3F800000u) < 0.f
                   ? -(float)m * 0.001953125f : (float)m * 0.001953125f;
  return __uint_as_float(s | ((e + 120u) << 23) | (m << 20));
}
// 8 fp8 (uint2) -> 8 bf16 fragment (exact: fp8 values are bf16-representable)
__device__ __forceinline__ bfx8 fp8x8_to_bf16x8(uint2 v){
#if __has_builtin(__builtin_amdgcn_cvt_pk_f32_fp8)
  typedef float fv2 __attribute__((ext_vector_type(2)));
  fv2 d0 = __builtin_amdgcn_cvt_pk_f32_fp8((int)v.x, false);
  fv2 d1 = __builtin_amdgcn_cvt_pk_f32_fp8((int)v.x, true);
  fv2 d2 = __builtin_amdgcn_cvt_pk_f32_fp8((int)v.y, false);
  fv2 d3 = __builtin_amdgcn_cvt_pk_f32_fp8((int)v.y, true);
  uint4 w{pkbf16(d0[0], d0[1]), pkbf16(d1[0], d1[1]),
          pkbf16(d2[0], d2[1]), pkbf16(d3[0], d3[1])};
  bfx8 r; __builtin_memcpy(&r, &w, 16); return r;
#else
  float f[8];
  f[0]=fp8d_sw(v.x&0xff); f[1]=fp8d_sw((v.x>>8)&0xff);
  f[2]=fp8d_sw((v.x>>16)&0xff); f[3]=fp8d_sw(v.x>>24);
  f[4]=fp8d_sw(v.y&0xff); f[5]=fp8d_sw((v.y>>8)&0xff);
  f[6]=fp8d_sw((v.y>>16)&0xff); f[7]=fp8d_sw(v.y>>24);
  return pack8(f);
#endif
}

// Uber-kernel; segments selected per-block by [nL1 | nL2 | nL3]:
//   blockIdx [0,nL1)            : L1 scan (f16-resident weights), h1 out FP8
//   blockIdx [nL1,nL1+nL2)      : L2 scan, MFMA proj on fp8->bf16 h1
//   blockIdx [nL1+nL2, +nL3)    : L3 scan, ONE WAVE PER CHAIN (barrier-free)
// Buffers are FULL-B; chunk bases cb1/cb2/cb3 are folded into h1/o2 indexing.
// HISTORY (do not regress):
//  - launch_bounds stays (512,2): (512,4) caps VGPR at 64 -> spill (r1).
//  - MFMA-batched L1 (r4-r6) latency-bound at 1 WG/CU. Reverted.
//  - r8: barrier-free 1-wave L3. r9: f16-resident L1 weights.
//  - r10/r11: issue cuts NULL -> scans latency-bound ~1670 cyc/step.
//  - r12: fp8 h1 interface passes with IDENTICAL absmax (error floor is the
//    bf16 o2 path). But flat same-stage 512-blk dispatches = 2 same-type
//    blocks/CU -> 1.7x per-stage slowdown (L2-all 2423us vs ring-mid 1430).
//  - r13: 2-chunk MIXED pipeline on full-B fp8 buffers: 4 dispatches, no
//    dispatch has >1 same-type block per CU (k1 pairs are 1xL1 + 1xL2).
__global__ __launch_bounds__(512, 2) void mega_kernel(
    int nL1, int nL2, int nL3, int cb1, int cb2, int cb3, int p1, int p2, int p3,
    const float* __restrict__ x,
    const float* __restrict__ Wih1, const float* __restrict__ Whh1,
    const float* __restrict__ bih1, const float* __restrict__ bhh1,
    const float* __restrict__ Wih2, const float* __restrict__ Whh2,
    const float* __restrict__ bih2, const float* __restrict__ bhh2,
    const float* __restrict__ Wih3, const float* __restrict__ Whh3,
    const float* __restrict__ bih3, const float* __restrict__ bhh3,
    unsigned char* __restrict__ h1r0, unsigned char* __restrict__ h1r1,
    unsigned short* __restrict__ o2r0, unsigned short* __restrict__ o2r1,
    float* __restrict__ sums)
{
  __shared__ __align__(16) unsigned char smem[34816];
  const int tid  = threadIdx.x;
  const int bid  = blockIdx.x;
  const int lane = tid & 63;
  const int wv   = tid >> 6;

  if (bid < nL1){
    // ================= L1: H=128, D=2 folded. WG = one (b,dir) chain. ======
    const int bloc = cb1 + (bid >> 1), dir = bid & 1;
    unsigned char* h1o = p1 ? h1r1 : h1r0;
    const int kc = tid & 3, u = tid >> 2;

    // Weights: 4 gate-rows x 32 K-elems as f16 pairs -> 64 VGPRs, RESIDENT.
    __half2 wh[4][16];
    const float* Wh = Whh1 + dir * 65536;
    #pragma unroll
    for (int g = 0; g < 4; ++g){
      const float* row = Wh + (g * 128 + u) * 128 + kc * 32;
      #pragma unroll
      for (int q = 0; q < 8; ++q){
        const int ro = (q + 2 * kc) & 7;
        const float4 t = *(const float4*)(row + ro * 4);
        wh[g][2 * q]     = __floats2half2_rn(t.x, t.y);
        wh[g][2 * q + 1] = __floats2half2_rn(t.z, t.w);
      }
    }
    float xwA[4], xwB[4], bs[4];
    #pragma unroll
    for (int g = 0; g < 4; ++g){
      const int r = g * 128 + u;
      xwA[g] = Wih1[dir * 1024 + r * 2];
      xwB[g] = Wih1[dir * 1024 + r * 2 + 1];
      bs[g]  = bih1[dir * 512 + r] + bhh1[dir * 512 + r];
    }
    float* xlds = (float*)smem;                  // 4096 f (full x row)
    float* hbuf = (float*)(smem + 16384);        // 2 x 128 f (fp32 state)
    {
      const float* xb = x + (size_t)bloc * (TL * 2);
      for (int idx = tid; idx < TL * 2; idx += 512) xlds[idx] = xb[idx];
    }
    if (tid < 128){ hbuf[tid] = 0.0f; hbuf[128 + tid] = 0.0f; }
    __syncthreads();

    float cst = 0.0f;
    for (int t = 0; t < TL; ++t){
      const int tt  = dir ? (TL - 1 - t) : t;
      const int cur = t & 1;
      const float4* hp = (const float4*)(hbuf + cur * 128) + kc * 8;
      float a0 = 0.f, a1 = 0.f, a2 = 0.f, a3 = 0.f;
      #pragma unroll
      for (int q = 0; q < 8; ++q){
        const float4 hv = hp[(q + 2 * kc) & 7];
        const __half2 w0a = wh[0][2*q], w0b = wh[0][2*q+1];
        const __half2 w1a = wh[1][2*q], w1b = wh[1][2*q+1];
        const __half2 w2a = wh[2][2*q], w2b = wh[2][2*q+1];
        const __half2 w3a = wh[3][2*q], w3b = wh[3][2*q+1];
        a0 = fmaf(__low2float(w0a), hv.x, a0); a0 = fmaf(__high2float(w0a), hv.y, a0);
        a0 = fmaf(__low2float(w0b), hv.z, a0); a0 = fmaf(__high2float(w0b), hv.w, a0);
        a1 = fmaf(__low2float(w1a), hv.x, a1); a1 = fmaf(__high2float(w1a), hv.y, a1);
        a1 = fmaf(__low2float(w1b), hv.z, a1); a1 = fmaf(__high2float(w1b), hv.w, a1);
        a2 = fmaf(__low2float(w2a), hv.x, a2); a2 = fmaf(__high2float(w2a), hv.y, a2);
        a2 = fmaf(__low2float(w2b), hv.z, a2); a2 = fmaf(__high2float(w2b), hv.w, a2);
        a3 = fmaf(__low2float(w3a), hv.x, a3); a3 = fmaf(__high2float(w3a), hv.y, a3);
        a3 = fmaf(__low2float(w3b), hv.z, a3); a3 = fmaf(__high2float(w3b), hv.w, a3);
      }
      a0 = dpp_xadd<0x4E>(dpp_xadd<0xB1>(a0));
      a1 = dpp_xadd<0x4E>(dpp_xadd<0xB1>(a1));
      a2 = dpp_xadd<0x4E>(dpp_xadd<0xB1>(a2));
      a3 = dpp_xadd<0x4E>(dpp_xadd<0xB1>(a3));
      if (kc == 0){
        const float x0 = xlds[tt * 2], x1 = xlds[tt * 2 + 1];
        const float p0 = a0 + fmaf(xwA[0], x0, fmaf(xwB[0], x1, bs[0]));
        const float p1 = a1 + fmaf(xwA[1], x0, fmaf(xwB[1], x1, bs[1]));
        const float p2 = a2 + fmaf(xwA[2], x0, fmaf(xwB[2], x1, bs[2]));
        const float p3 = a3 + fmaf(xwA[3], x0, fmaf(xwB[3], x1, bs[3]));
        const float ig = sigf(p0), fg = sigf(p1), gg = tanhff(p2), og = sigf(p3);
        cst = fmaf(fg, cst, ig * gg);
        const float h = og * tanhff(cst);
        hbuf[(cur ^ 1) * 128 + u] = h;                       // fp32 recurrence
        h1o[((size_t)bloc * TL + tt) * 256 + dir * 128 + u] = f2fp8(h);
      }
      barrier_lgkm();
    }

  } else if (bid < nL1 + nL2){
    // ================= L2: H=64; proj (K=256) via MFMA lookahead. ==========
    const int i2 = bid - nL1;
    const int bloc = cb2 + (i2 >> 1), dir = i2 & 1;
    const unsigned char* h1i = (p2 ? h1r1 : h1r0) + (size_t)bloc * TL * 256;
    unsigned short* o2o = p2 ? o2r1 : o2r0;
    const int kc = tid & 7, u = tid >> 3;

    float4 wr[4][2]; float bs[4];
    const float* WR = Whh2 + dir * 16384;
    #pragma unroll
    for (int tgt = 0; tgt < 4; ++tgt){
      const int row = tgt * 64 + u;
      wr[tgt][0] = *(const float4*)(WR + row * 64 + kc * 8);
      wr[tgt][1] = *(const float4*)(WR + row * 64 + kc * 8 + 4);
      bs[tgt] = bih2[dir * 256 + row] + bhh2[dir * 256 + row];
    }
    bfx8 Bf[2][8];
    const float* WP = Wih2 + dir * 65536;
    #pragma unroll
    for (int ntl = 0; ntl < 2; ++ntl){
      const int n = (2 * wv + ntl) * 16 + (lane & 15);
      #pragma unroll
      for (int Kf = 0; Kf < 8; ++Kf)
        Bf[ntl][Kf] = pack8(WP + n * 256 + Kf * 32 + (lane >> 4) * 8);
    }
    float* xs  = (float*)smem;                   // 2 bufs x 16 x 258 f
    float* h2b = (float*)(smem + 33024);         // 2 x 64 f
    if (tid < 64){ h2b[tid] = 0.0f; h2b[64 + tid] = 0.0f; }

    auto loadA = [&](int blk, uint2* a8){
      const int m  = lane & 15;
      const int pt = dir ? (TL - 1 - (blk * 16 + m)) : (blk * 16 + m);
      const unsigned char* base = h1i + (size_t)pt * 256 + (lane >> 4) * 8;
      #pragma unroll
      for (int Kf = 0; Kf < 8; ++Kf) a8[Kf] = *(const uint2*)(base + Kf * 32);
    };
    auto domfma = [&](uint2* a8, int buf){
      fx4 acc0 = {0.f,0.f,0.f,0.f}, acc1 = {0.f,0.f,0.f,0.f};
      #pragma unroll
      for (int Kf = 0; Kf < 8; ++Kf){
        const bfx8 av = fp8x8_to_bf16x8(a8[Kf]);
        acc0 = __builtin_amdgcn_mfma_f32_16x16x32_bf16(av, Bf[0][Kf], acc0, 0, 0, 0);
        acc1 = __builtin_amdgcn_mfma_f32_16x16x32_bf16(av, Bf[1][Kf], acc1, 0, 0, 0);
      }
      const int c0 = (2 * wv) * 16 + (lane & 15);
      #pragma unroll
      for (int rr = 0; rr < 4; ++rr){
        const int row = (lane >> 4) * 4 + rr;
        xs[buf * 4128 + row * 258 + c0]      = acc0[rr];
        xs[buf * 4128 + row * 258 + c0 + 16] = acc1[rr];
      }
    };

    uint2 a8[8];
    loadA(0, a8); domfma(a8, 0);
    loadA(1, a8); domfma(a8, 1);
    __syncthreads();

    float cst = 0.0f;
    uint2 pf[8];
    for (int B = 0; B < 128; ++B){
      if (B + 2 < 128) loadA(B + 2, pf);      // issue; consumed after the 16 steps
      const int pb = B & 1;
      for (int s = 0; s < 16; ++s){
        const int t  = B * 16 + s;
        const int tt = dir ? (TL - 1 - t) : t;
        const int cur = t & 1;
        const float4* hv4 = (const float4*)(h2b + cur * 64) + kc * 2;
        const float4 hA = hv4[0], hB = hv4[1];
        float a0 = dot4(wr[0][1], hB, dot4(wr[0][0], hA, 0.f));
        float a1 = dot4(wr[1][1], hB, dot4(wr[1][0], hA, 0.f));
        float a2 = dot4(wr[2][1], hB, dot4(wr[2][0], hA, 0.f));
        float a3 = dot4(wr[3][1], hB, dot4(wr[3][0], hA, 0.f));
        // 8-way kc reduce entirely in the VALU pipe (r11).
        a0 = dpp_xadd<0x141>(dpp_xadd<0x4E>(dpp_xadd<0xB1>(a0)));
        a1 = dpp_xadd<0x141>(dpp_xadd<0x4E>(dpp_xadd<0xB1>(a1)));
        a2 = dpp_xadd<0x141>(dpp_xadd<0x4E>(dpp_xadd<0xB1>(a2)));
        a3 = dpp_xadd<0x141>(dpp_xadd<0x4E>(dpp_xadd<0xB1>(a3)));
        if (kc == 0){
          const float* xr = xs + pb * 4128 + s * 258 + u;
          const float ig = sigf(a0 + xr[0]   + bs[0]);
          const float fg = sigf(a1 + xr[64]  + bs[1]);
          const float gg = tanhff(a2 + xr[128] + bs[2]);
          const float og = sigf(a3 + xr[192] + bs[3]);
          cst = fmaf(fg, cst, ig * gg);
          const float h = og * tanhff(cst);
          h2b[(cur ^ 1) * 64 + u] = h;
          o2o[((size_t)bloc * TL + tt) * 128 + dir * 64 + u] = f2bf(h);
        }
        barrier_lgkm();
      }
      if (B + 2 < 128) domfma(pf, pb);        // fills buf pb for block B+2
    }

  } else {
    // ========== L3: H=16; ONE WAVE PER CHAIN, barrier-free (r8). ==========
    const int i3 = bid - nL1 - nL2;
    const int mm  = lane & 15;
    const int gg4 = lane >> 4;               // gate id (i,f,g,o) for this lane

    unsigned short* wlds = (unsigned short*)smem;   // 32768 B: [dir][64][128] bf16
    float* h3b = (float*)(smem + 32768);            // 4 ch x 2 x 16 f = 512 B
    for (int idx = tid; idx < 8192; idx += 512){
      const float2 v = *(const float2*)(Wih3 + idx * 2);
      const unsigned off = idx * 4u;
      const unsigned sw  = off ^ ((((off >> 8) & 7u)) << 4);
      *(unsigned*)((unsigned char*)wlds + sw) =
          (unsigned)f2bf(v.x) | ((unsigned)f2bf(v.y) << 16);
    }
    if (tid < 128) h3b[tid] = 0.0f;
    __syncthreads();
    if (wv >= 4) return;                      // idle waves exit; no barriers follow

    const int chain = i3 * 4 + wv;
    const int bloc = cb3 + (chain >> 1), dir = chain & 1;
    const unsigned short* o2i = (p3 ? o2r1 : o2r0) + (size_t)bloc * TL * 128;

    const float* WR = Whh3 + dir * 1024 + (gg4 * 16 + mm) * 16;
    const float4 wr0 = *(const float4*)(WR);
    const float4 wr1 = *(const float4*)(WR + 4);
    const float4 wr2 = *(const float4*)(WR + 8);
    const float4 wr3 = *(const float4*)(WR + 12);
    const float bsv = bih3[dir * 64 + gg4 * 16 + mm] + bhh3[dir * 64 + gg4 * 16 + mm];

    float* hme = h3b + wv * 32;

    uint4 a4[4];
    auto loadA3 = [&](int blk){
      const int pt = dir ? (TL - 1 - (blk * 16 + mm)) : (blk * 16 + mm);
      const unsigned short* bptr = o2i + (size_t)pt * 128 + (lane >> 4) * 8;
      #pragma unroll
      for (int Kf = 0; Kf < 4; ++Kf) a4[Kf] = *(const uint4*)(bptr + Kf * 32);
    };
    fx4 ac0, ac1, ac2, ac3;
    auto domfma3 = [&](){
      ac0 = fx4{0.f,0.f,0.f,0.f}; ac1 = fx4{0.f,0.f,0.f,0.f};
      ac2 = fx4{0.f,0.f,0.f,0.f}; ac3 = fx4{0.f,0.f,0.f,0.f};
      #pragma unroll
      for (int Kf = 0; Kf < 4; ++Kf){
        bfx8 av; __builtin_memcpy(&av, &a4[Kf], 16);
        #pragma unroll
        for (int gt = 0; gt < 4; ++gt){
          unsigned boff = dir * 16384u + (unsigned)(gt * 16 + mm) * 256u
                        + (unsigned)(Kf * 32 + (lane >> 4) * 8) * 2u;
          boff ^= ((unsigned)(mm & 7) << 4);
          bfx8 bv; __builtin_memcpy(&bv, (unsigned char*)wlds + boff, 16);
          if (gt == 0) ac0 = __builtin_amdgcn_mfma_f32_16x16x32_bf16(av, bv, ac0, 0,0,0);
          else if (gt == 1) ac1 = __builtin_amdgcn_mfma_f32_16x16x32_bf16(av, bv, ac1, 0,0,0);
          else if (gt == 2) ac2 = __builtin_amdgcn_mfma_f32_16x16x32_bf16(av, bv, ac2, 0,0,0);
          else ac3 = __builtin_amdgcn_mfma_f32_16x16x32_bf16(av, bv, ac3, 0,0,0);
        }
      }
    };

    loadA3(0); domfma3(); loadA3(1);

    float cst = 0.0f, msum = 0.0f;
    for (int B = 0; B < 128; ++B){
      #pragma unroll
      for (int s = 0; s < 16; ++s){
        const int t = B * 16 + s;
        const int cur = t & 1;
        const float* hb = hme + cur * 16;
        const float4 h0 = *(const float4*)(hb);
        const float4 h1 = *(const float4*)(hb + 4);
        const float4 h2 = *(const float4*)(hb + 8);
        const float4 h3v = *(const float4*)(hb + 12);
        const float rec = dot4(wr3, h3v, dot4(wr2, h2, dot4(wr1, h1, dot4(wr0, h0, 0.f))));
        const int src = (s >> 2) * 16 + mm;
        const float p0 = bperm(ac0[s & 3], src);
        const float p1 = bperm(ac1[s & 3], src);
        const float p2 = bperm(ac2[s & 3], src);
        const float p3 = bperm(ac3[s & 3], src);
        const float pj = (gg4 == 0) ? p0 : (gg4 == 1) ? p1 : (gg4 == 2) ? p2 : p3;
        const float pre = rec + pj + bsv;
        const float sg = sigf((gg4 == 2) ? 2.0f * pre : pre);
        const float act = (gg4 == 2) ? fmaf(2.0f, sg, -1.0f) : sg;
        const float gI = bperm(act, mm);
        const float gF = bperm(act, mm + 16);
        const float gG = bperm(act, mm + 32);
        const float gO = bperm(act, mm + 48);
        if (lane < 16){
          cst = fmaf(gF, cst, gI * gG);
          const float h = gO * tanhff(cst);
          hme[(cur ^ 1) * 16 + mm] = h;
          msum += h;
        }
      }
      if (B + 1 < 128){ domfma3(); if (B + 2 < 128) loadA3(B + 2); }
    }
    if (lane < 16) sums[(size_t)bloc * 32 + dir * 16 + mm] = msum;
  }
}

// ---------------- head: mean (pre-summed) + MLP, one 64-thr WG per batch
__global__ __launch_bounds__(64) void head_kernel(
    const float* __restrict__ sums,
    const float* __restrict__ hW1, const float* __restrict__ hb1,
    const float* __restrict__ hW2, const float* __restrict__ hb2,
    const float* __restrict__ hW3, const float* __restrict__ hb3,
    float* __restrict__ out)
{
  __shared__ float m[32], h1s[64], h2s[16];
  const int tid = threadIdx.x, b = blockIdx.x;
  if (tid < 32) m[tid] = sums[b * 32 + tid] * (1.0f / 2048.0f);
  __syncthreads();
  {
    float a = hb1[tid];
    #pragma unroll
    for (int k = 0; k < 32; ++k) a = fmaf(m[k], hW1[tid * 32 + k], a);
    h1s[tid] = fmaxf(a, 0.0f);
  }
  __syncthreads();
  if (tid < 16){
    float a = hb2[tid];
    #pragma unroll
    for (int k = 0; k < 64; ++k) a = fmaf(h1s[k], hW2[tid * 64 + k], a);
    h2s[tid] = fmaxf(a, 0.0f);
  }
  __syncthreads();
  if (tid < 20){
    float a = hb3[tid];
    #pragma unroll
    for (int k = 0; k < 16; ++k) a = fmaf(h2s[k], hW3[tid * 16 + k], a);
    out[b * 20 + tid] = a;
  }
}

extern "C" void kernel_launch(void* const* d_in, const int* in_sizes, int n_in,
                              void* d_out, int out_size, void* d_ws, size_t ws_size,
                              hipStream_t stream) {
  (void)in_sizes; (void)n_in; (void)out_size;
  const float* x    = (const float*)d_in[0];
  const float* Wih1 = (const float*)d_in[1];
  const float* Whh1 = (const float*)d_in[2];
  const float* bih1 = (const float*)d_in[3];
  const float* bhh1 = (const float*)d_in[4];
  const float* Wih2 = (const float*)d_in[5];
  const float* Whh2 = (const float*)d_in[6];
  const float* bih2 = (const float*)d_in[7];
  const float* bhh2 = (const float*)d_in[8];
  const float* Wih3 = (const float*)d_in[9];
  const float* Whh3 = (const float*)d_in[10];
  const float* bih3 = (const float*)d_in[11];
  const float* bhh3 = (const float*)d_in[12];
  const float* hW1  = (const float*)d_in[13];
  const float* hb1  = (const float*)d_in[14];
  const float* hW2  = (const float*)d_in[15];
  const float* hb2  = (const float*)d_in[16];
  const float* hW3  = (const float*)d_in[17];
  const float* hb3  = (const float*)d_in[18];
  unsigned char* ws = (unsigned char*)d_ws;

  if (ws_size >= 268468224ull) {
    // ===== 2-chunk MIXED pipeline on full-B buffers (4 mega dispatches).
    // h1 fp8 (256,2048,256) = 134,217,728 B | o2 bf16 (256,2048,128) =
    // 134,217,728 B | sums 32,768 B. Total 268,468,224 <= proven ws
    // (>=276,856,832, round 3). Chunks A=[0,128), B=[128,256).
    // k1 block order: 0..255 = L1(B), 256..511 = L2(A) -> the CP fills each
    // CU with one L1 block first, then one L2 block: MIXED pairs only.
    unsigned char*  h1 = ws;
    unsigned short* o2 = (unsigned short*)(ws + 134217728u);
    float* sums = (float*)(ws + 268435456u);
    mega_kernel<<<dim3(256), dim3(512), 0, stream>>>(   // k0: L1(A)
        256, 0, 0, 0, 0, 0, 0, 0, 0,
        x, Wih1, Whh1, bih1, bhh1, Wih2, Whh2, bih2, bhh2,
        Wih3, Whh3, bih3, bhh3, h1, h1, o2, o2, sums);
    mega_kernel<<<dim3(512), dim3(512), 0, stream>>>(   // k1: L1(B) + L2(A)
        256, 256, 0, 128, 0, 0, 0, 0, 0,
        x, Wih1, Whh1, bih1, bhh1, Wih2, Whh2, bih2, bhh2,
        Wih3, Whh3, bih3, bhh3, h1, h1, o2, o2, sums);
    mega_kernel<<<dim3(320), dim3(512), 0, stream>>>(   // k2: L2(B) + L3(A)
        0, 256, 64, 0, 128, 0, 0, 0, 0,
        x, Wih1, Whh1, bih1, bhh1, Wih2, Whh2, bih2, bhh2,
        Wih3, Whh3, bih3, bhh3, h1, h1, o2, o2, sums);
    mega_kernel<<<dim3(64), dim3(512), 0, stream>>>(    // k3: L3(B)
        0, 0, 64, 0, 0, 128, 0, 0, 0,
        x, Wih1, Whh1, bih1, bhh1, Wih2, Whh2, bih2, bhh2,
        Wih3, Whh3, bih3, bhh3, h1, h1, o2, o2, sums);
    head_kernel<<<dim3(256), dim3(64), 0, stream>>>(
        sums, hW1, hb1, hW2, hb2, hW3, hb3, (float*)d_out);
    return;
  }

  // ===== Fallback (unreachable given established ws bracket): serial
  // 2-chunk schedule on chunk-sized buffers, cb folded out via pointer
  // adjustment (each dispatch touches exactly one chunk per buffer).
  {
    const size_t H1C = (size_t)128 * TL * 256;        // 67,108,864 B (fp8)
    const size_t O2C = (size_t)128 * TL * 128 * 2;    // 67,108,864 B (bf16)
    unsigned char*  h1c = ws;
    unsigned short* o2c = (unsigned short*)(ws + H1C);
    float* sums = (float*)(ws + H1C + O2C);
    for (int c = 0; c < 2; ++c){
      const int cb = c * 128;
      unsigned char*  h1a = h1c - (size_t)cb * TL * 256;
      unsigned short* o2a = (unsigned short*)((unsigned char*)o2c
                              - (size_t)cb * TL * 256);
      mega_kernel<<<dim3(256), dim3(512), 0, stream>>>(
          256, 0, 0, cb, 0, 0, 0, 0, 0,
          x, Wih1, Whh1, bih1, bhh1, Wih2, Whh2, bih2, bhh2,
          Wih3, Whh3, bih3, bhh3, h1a, h1a, o2a, o2a, sums);
      mega_kernel<<<dim3(256), dim3(512), 0, stream>>>(
          0, 256, 0, 0, cb, 0, 0, 0, 0,
          x, Wih1, Whh1, bih1, bhh1, Wih2, Whh2, bih2, bhh2,
          Wih3, Whh3, bih3, bhh3, h1a, h1a, o2a, o2a, sums);
      mega_kernel<<<dim3(64), dim3(512), 0, stream>>>(
          0, 0, 64, 0, 0, cb, 0, 0, 0,
          x, Wih1, Whh1, bih1, bhh1, Wih2, Whh2, bih2, bhh2,
          Wih3, Whh3, bih3, bhh3, h1a, h1a, o2a, o2a, sums);
    }
    head_kernel<<<dim3(256), dim3(64), 0, stream>>>(
        sums, hW1, hb1, hW2, hb2, hW3, hb3, (float*)d_out);
  }
}